// Round 2
// baseline (994.329 us; speedup 1.0000x reference)
//
#include <hip/hip_runtime.h>
#include <hip/hip_bf16.h>
#include <stdint.h>

// Problem constants
constexpr int cB = 4, cN = 512, cE = 512, cH = 32, cP = 128;
// D = 16, SCALING = 0.25 folded into Q at projection epilogue.

typedef __attribute__((ext_vector_type(8))) short bf16x8;
typedef __attribute__((ext_vector_type(4))) float f32x4;

__device__ __forceinline__ unsigned short f2bf(float f) {
    union { float f; unsigned u; } v; v.f = f;
    unsigned u = v.u;
    u += 0x7fffu + ((u >> 16) & 1u);   // RNE
    return (unsigned short)(u >> 16);
}

// ---------------- Kernel 1: LayerNorm(query) -> xn (f32) ----------------
__global__ __launch_bounds__(256) void ln_query_kernel(
    const float* __restrict__ q, const float* __restrict__ g,
    const float* __restrict__ b, float* __restrict__ xn)
{
    int row = blockIdx.x;          // 0..B*N-1
    int t = threadIdx.x;           // 256
    const float* xr = q + (size_t)row * cE;
    float2 v = *(const float2*)(xr + t * 2);
    float s = v.x + v.y;
    float ss = v.x * v.x + v.y * v.y;
    #pragma unroll
    for (int o = 32; o > 0; o >>= 1) {
        s  += __shfl_down(s, o, 64);
        ss += __shfl_down(ss, o, 64);
    }
    __shared__ float red[8];
    int wv = t >> 6, ln = t & 63;
    if (ln == 0) { red[wv] = s; red[wv + 4] = ss; }
    __syncthreads();
    if (t == 0) {
        float S = red[0] + red[1] + red[2] + red[3];
        float SS = red[4] + red[5] + red[6] + red[7];
        float mu = S * (1.0f / cE);
        float var = SS * (1.0f / cE) - mu * mu;
        red[0] = mu; red[1] = rsqrtf(var + 1e-5f);
    }
    __syncthreads();
    float mu = red[0], rs = red[1];
    float2 gg = *(const float2*)(g + t * 2);
    float2 bb2 = *(const float2*)(b + t * 2);
    float2 o2;
    o2.x = (v.x - mu) * rs * gg.x + bb2.x;
    o2.y = (v.y - mu) * rs * gg.y + bb2.y;
    *(float2*)(xn + (size_t)row * cE + t * 2) = o2;
}

// ---------------- Kernel 2: setup Wb' (bf16), S_h, cb_h ----------------
__global__ __launch_bounds__(256) void setup_kernel(
    const float* __restrict__ Wb, const float* __restrict__ pg,
    const float* __restrict__ pb, const float* __restrict__ bbv,
    unsigned short* __restrict__ Wbp, float* __restrict__ Sh,
    float* __restrict__ cbh)
{
    int t = threadIdx.x;
    int h = t >> 3, sub = t & 7;       // 32 heads x 8 lanes, 16 p each
    float s = 0.f, c = 0.f;
    #pragma unroll
    for (int pp = 0; pp < 16; ++pp) {
        int p = sub * 16 + pp;
        float wv = Wb[h * cP + p];
        float wp = wv * pg[p];
        s += wp;
        c = fmaf(pb[p], wv, c);
        Wbp[h * cP + p] = f2bf(wp);
    }
    s += __shfl_xor(s, 1, 64); s += __shfl_xor(s, 2, 64); s += __shfl_xor(s, 4, 64);
    c += __shfl_xor(c, 1, 64); c += __shfl_xor(c, 2, 64); c += __shfl_xor(c, 4, 64);
    if (sub == 0) { Sh[h] = s; cbh[h] = c + bbv[h]; }
}

// ------------- Kernel 3: Q/K projections (fp32 GEMM) + w from V tile -------------
// 256 threads, 64x64 tile, 4x4 micro-tile, register-prefetch double staging.
__global__ __launch_bounds__(256) void qkv_kernel(
    const float* __restrict__ xn,
    const float* __restrict__ Wq, const float* __restrict__ Wk,
    const float* __restrict__ Wv, const float* __restrict__ Wf,
    float* __restrict__ Q, float* __restrict__ K, float* __restrict__ w)
{
    int mtile = blockIdx.x & 31;      // 32 tiles of 64 rows
    int ntile = blockIdx.x >> 5;      // 24 tiles of 64 cols
    int mat = ntile >> 3;             // 0=Q 1=K 2=V
    int ncol0 = (ntile & 7) * 64;
    const float* W = (mat == 0) ? Wq : ((mat == 1) ? Wk : Wv);
    int rm = mtile * 64;
    int t = threadIdx.x;
    int tm = t >> 4, tn = t & 15;     // 16x16 thread grid, 4x4 micro-tile

    __shared__ float As[32][68];      // [k][m]
    __shared__ float Bs[32][68];      // [k][n]
    float acc[4][4] = {{0.f}};
    float4 pa[2], pb2[2];

    auto stage_load = [&](int k0) {
        #pragma unroll
        for (int s = 0; s < 2; ++s) {
            int f = t + 256 * s;      // 0..511 float4 slots
            int row = f >> 3, kq = f & 7;
            pa[s]  = *(const float4*)(xn + (size_t)(rm + row) * cE + k0 + kq * 4);
            pb2[s] = *(const float4*)(W + (size_t)(ncol0 + row) * cE + k0 + kq * 4);
        }
    };
    stage_load(0);

    for (int k0 = 0; k0 < cE; k0 += 32) {
        __syncthreads();
        #pragma unroll
        for (int s = 0; s < 2; ++s) {
            int f = t + 256 * s;
            int row = f >> 3, kq = f & 7;
            As[kq * 4 + 0][row] = pa[s].x; As[kq * 4 + 1][row] = pa[s].y;
            As[kq * 4 + 2][row] = pa[s].z; As[kq * 4 + 3][row] = pa[s].w;
            Bs[kq * 4 + 0][row] = pb2[s].x; Bs[kq * 4 + 1][row] = pb2[s].y;
            Bs[kq * 4 + 2][row] = pb2[s].z; Bs[kq * 4 + 3][row] = pb2[s].w;
        }
        __syncthreads();
        if (k0 + 32 < cE) stage_load(k0 + 32);
        #pragma unroll
        for (int kk = 0; kk < 32; ++kk) {
            float4 av = *(const float4*)&As[kk][tm * 4];
            float4 bv = *(const float4*)&Bs[kk][tn * 4];
            float ar[4] = {av.x, av.y, av.z, av.w};
            float br[4] = {bv.x, bv.y, bv.z, bv.w};
            #pragma unroll
            for (int i2 = 0; i2 < 4; ++i2)
                #pragma unroll
                for (int j2 = 0; j2 < 4; ++j2)
                    acc[i2][j2] = fmaf(ar[i2], br[j2], acc[i2][j2]);
        }
    }

    if (mat < 2) {
        float scale = (mat == 0) ? 0.25f : 1.0f;
        float* dst = (mat == 0) ? Q : K;
        #pragma unroll
        for (int i2 = 0; i2 < 4; ++i2) {
            int r = rm + tm * 4 + i2;
            #pragma unroll
            for (int j2 = 0; j2 < 4; ++j2)
                dst[(size_t)r * cE + ncol0 + tn * 4 + j2] = acc[i2][j2] * scale;
        }
    } else {
        int col0 = ncol0 + tn * 4;
        int hh = col0 >> 4;           // 4 cols all in one head (4-aligned within 16)
        float wf[4];
        #pragma unroll
        for (int j2 = 0; j2 < 4; ++j2) wf[j2] = Wf[col0 + j2];
        #pragma unroll
        for (int i2 = 0; i2 < 4; ++i2) {
            int r = rm + tm * 4 + i2;
            float part = 0.f;
            #pragma unroll
            for (int j2 = 0; j2 < 4; ++j2) part = fmaf(acc[i2][j2], wf[j2], part);
            atomicAdd(&w[(size_t)r * cH + hh], part);
        }
    }
}

// ------------- Kernel 4: fused bias-GEMM + attention + force (per (b,i)) -------------
// Pair tile lives in REGISTERS (each lane loads exactly its MFMA A-fragment);
// LN stats via shfl quad-reduce from the same regs; 1 barrier per j-tile.
__global__ __launch_bounds__(256) void attn_kernel(
    const float* __restrict__ pair, const float* __restrict__ mask,
    const float* __restrict__ dpos, const float* __restrict__ Q,
    const float* __restrict__ K, const float* __restrict__ w,
    const unsigned short* __restrict__ Wbp, const float* __restrict__ Sh_g,
    const float* __restrict__ cb_g, float* __restrict__ out)
{
    int bi = blockIdx.x;              // b*N + i
    int b = bi >> 9, i = bi & 511;
    int t = threadIdx.x;
    int lane = t & 63, wv = t >> 6;

    __shared__ __align__(16) unsigned short Bw[32 * 136];  // Wb' bf16 [h][p], padded
    __shared__ float biasT[2][64][33];   // raw dots [j][h], double-buffered
    __shared__ float mt[2][64][33];      // mask tile [j][h]; buf0 reused as reduce scratch
    __shared__ float qrow[512];
    __shared__ float mrow[2][64], rrow[2][64];
    __shared__ float dl[2][192];
    __shared__ float Shs[32], cbs[32];

    // stage Wb' (once)
    {
        const ushort4* src = (const ushort4*)Wbp;
        #pragma unroll
        for (int s = 0; s < 4; ++s) {
            int f = t + 256 * s;      // 0..1023 ushort4 slots
            int hh = f >> 5, p4 = f & 31;
            ushort4 v = src[f];
            *(ushort4*)&Bw[hh * 136 + p4 * 4] = v;
        }
    }
    if (t < 128) {
        float4 qv = *(const float4*)(Q + (size_t)bi * cE + t * 4);
        *(float4*)&qrow[t * 4] = qv;
    }
    if (t < 32) { Shs[t] = Sh_g[t]; cbs[t] = cb_g[t]; }

    const float* pbase = pair + (size_t)bi * cN * cP;
    const float* dbase = dpos + (size_t)bi * cN * 3;
    const float* Kbase = K + (size_t)b * cN * cE;
    const float* wbase = w + (size_t)b * cN * cH;
    const float* mbase = mask + ((size_t)b * cH * cN + i) * cN;  // + hh*N*N + col

    int arow = wv * 16 + (lane & 15);   // pair row within 64-tile this lane feeds MFMA
    int kcol = (lane >> 4) * 8;         // k-chunk base within each 32-k block

    float4 pf[8]; float4 mf[2]; float dreg = 0.f;
    auto loadregs = [&](int j0) {
        const float* prow = pbase + (size_t)(j0 + arow) * cP + kcol;
        #pragma unroll
        for (int kb = 0; kb < 4; ++kb) {
            pf[2 * kb]     = *(const float4*)(prow + kb * 32);
            pf[2 * kb + 1] = *(const float4*)(prow + kb * 32 + 4);
        }
        #pragma unroll
        for (int s = 0; s < 2; ++s) {
            int f = t + 256 * s;      // 0..511
            int hh = f >> 4, c4 = f & 15;
            mf[s] = *(const float4*)(mbase + (size_t)hh * cN * cN + j0 + c4 * 4);
        }
        if (t < 192) dreg = dbase[j0 * 3 + t];
    };

    loadregs(0);
    __syncthreads();                  // Bw, qrow, Shs visible

    int h = t & 31, js = t >> 5;      // softmax mapping: head h, j-slice js (8 slices)
    float qreg[16];
    #pragma unroll
    for (int d = 0; d < 16; ++d) qreg[d] = qrow[h * 16 + d];
    float Sh_loc = Shs[h], cb_loc = cbs[h];

    float m = -1e30f, l = 0.f, a0 = 0.f, a1 = 0.f, a2 = 0.f;

    for (int it = 0; it < 8; ++it) {
        int cur = it & 1;
        int j0 = it * 64;

        // ---- compute phase: cvt + stats + MFMA + aux LDS writes ----
        bf16x8 af[4];
        float s1 = 0.f, s2 = 0.f;
        #pragma unroll
        for (int kb = 0; kb < 4; ++kb) {
            float4 u0 = pf[2 * kb], u1 = pf[2 * kb + 1];
            s1 += u0.x + u0.y + u0.z + u0.w + u1.x + u1.y + u1.z + u1.w;
            s2 = fmaf(u0.x, u0.x, s2); s2 = fmaf(u0.y, u0.y, s2);
            s2 = fmaf(u0.z, u0.z, s2); s2 = fmaf(u0.w, u0.w, s2);
            s2 = fmaf(u1.x, u1.x, s2); s2 = fmaf(u1.y, u1.y, s2);
            s2 = fmaf(u1.z, u1.z, s2); s2 = fmaf(u1.w, u1.w, s2);
            bf16x8 a;
            a[0] = (short)f2bf(u0.x); a[1] = (short)f2bf(u0.y);
            a[2] = (short)f2bf(u0.z); a[3] = (short)f2bf(u0.w);
            a[4] = (short)f2bf(u1.x); a[5] = (short)f2bf(u1.y);
            a[6] = (short)f2bf(u1.z); a[7] = (short)f2bf(u1.w);
            af[kb] = a;
        }
        s1 += __shfl_xor(s1, 16, 64); s1 += __shfl_xor(s1, 32, 64);
        s2 += __shfl_xor(s2, 16, 64); s2 += __shfl_xor(s2, 32, 64);
        if ((lane >> 4) == 0) {
            float mu = s1 * (1.0f / cP);
            float var = s2 * (1.0f / cP) - mu * mu;
            mrow[cur][arow] = mu;
            rrow[cur][arow] = rsqrtf(var + 1e-5f);
        }
        {
            f32x4 acc0 = {0.f, 0.f, 0.f, 0.f}, acc1 = {0.f, 0.f, 0.f, 0.f};
            #pragma unroll
            for (int kb = 0; kb < 4; ++kb) {
                int k = kb * 32 + kcol;
                bf16x8 b0 = *(const bf16x8*)&Bw[(lane & 15) * 136 + k];
                bf16x8 b1 = *(const bf16x8*)&Bw[(16 + (lane & 15)) * 136 + k];
                acc0 = __builtin_amdgcn_mfma_f32_16x16x32_bf16(af[kb], b0, acc0, 0, 0, 0);
                acc1 = __builtin_amdgcn_mfma_f32_16x16x32_bf16(af[kb], b1, acc1, 0, 0, 0);
            }
            int crow = wv * 16 + (lane >> 4) * 4;
            int ccol = lane & 15;
            #pragma unroll
            for (int r = 0; r < 4; ++r) {
                biasT[cur][crow + r][ccol] = acc0[r];
                biasT[cur][crow + r][16 + ccol] = acc1[r];
            }
        }
        #pragma unroll
        for (int s = 0; s < 2; ++s) {
            int f = t + 256 * s;
            int hh = f >> 4, c4 = f & 15;
            mt[cur][c4 * 4 + 0][hh] = mf[s].x;
            mt[cur][c4 * 4 + 1][hh] = mf[s].y;
            mt[cur][c4 * 4 + 2][hh] = mf[s].z;
            mt[cur][c4 * 4 + 3][hh] = mf[s].w;
        }
        if (t < 192) dl[cur][t] = dreg;

        __syncthreads();              // the ONLY barrier per iteration

        if (it < 7) loadregs(j0 + 64);  // prefetch: no barrier until consumption

        // ---- logits + online softmax + accumulation ----
        #pragma unroll
        for (int jj = 0; jj < 8; ++jj) {
            int jr = js * 8 + jj;
            int j = j0 + jr;
            float bias = rrow[cur][jr] * (biasT[cur][jr][h] - mrow[cur][jr] * Sh_loc) + cb_loc;
            const float4* kp4 = (const float4*)(Kbase + (size_t)j * cE + h * 16);
            float qk = 0.f;
            #pragma unroll
            for (int d4 = 0; d4 < 4; ++d4) {
                float4 kv = kp4[d4];
                qk = fmaf(qreg[d4 * 4 + 0], kv.x, qk);
                qk = fmaf(qreg[d4 * 4 + 1], kv.y, qk);
                qk = fmaf(qreg[d4 * 4 + 2], kv.z, qk);
                qk = fmaf(qreg[d4 * 4 + 3], kv.w, qk);
            }
            float z = qk + bias + mt[cur][jr][h];
            float wj = wbase[(size_t)j * cH + h];
            float mn = fmaxf(m, z);
            float sc = __expf(m - mn);
            float p = __expf(z - mn);
            l = l * sc + p;
            float pw = p * wj;
            a0 = fmaf(pw, dl[cur][jr * 3 + 0], a0 * sc);
            a1 = fmaf(pw, dl[cur][jr * 3 + 1], a1 * sc);
            a2 = fmaf(pw, dl[cur][jr * 3 + 2], a2 * sc);
            m = mn;
        }
    }

    // ---- merge 8 js-slices per head, then sum over heads ----
    // scratch = mt buffer 0 (last softmax read buffer 1; distinct memory)
    float* red = &mt[0][0][0];
    red[(h * 8 + js) * 6 + 0] = m;
    red[(h * 8 + js) * 6 + 1] = l;
    red[(h * 8 + js) * 6 + 2] = a0;
    red[(h * 8 + js) * 6 + 3] = a1;
    red[(h * 8 + js) * 6 + 4] = a2;
    __syncthreads();
    for (int s = 4; s >= 1; s >>= 1) {
        if (js < s) {
            float* p1 = &red[(h * 8 + js) * 6];
            float* p2 = &red[(h * 8 + js + s) * 6];
            float m1 = p1[0], m2 = p2[0];
            float mn = fmaxf(m1, m2);
            float e1 = __expf(m1 - mn), e2 = __expf(m2 - mn);
            p1[0] = mn;
            p1[1] = p1[1] * e1 + p2[1] * e2;
            p1[2] = p1[2] * e1 + p2[2] * e2;
            p1[3] = p1[3] * e1 + p2[3] * e2;
            p1[4] = p1[4] * e1 + p2[4] * e2;
        }
        __syncthreads();
    }
    if (js == 0) {
        float linv = 1.0f / red[h * 48 + 1];
        biasT[0][h][0] = red[h * 48 + 2] * linv;
        biasT[0][h][1] = red[h * 48 + 3] * linv;
        biasT[0][h][2] = red[h * 48 + 4] * linv;
    }
    __syncthreads();
    if (t < 3) {
        float s = 0.f;
        #pragma unroll
        for (int hh = 0; hh < cH; ++hh) s += biasT[0][hh][t];
        out[(size_t)bi * 3 + t] = s;
    }
}

// ---------------------------------------------------------------
extern "C" void kernel_launch(void* const* d_in, const int* in_sizes, int n_in,
                              void* d_out, int out_size, void* d_ws, size_t ws_size,
                              hipStream_t stream)
{
    const float* query = (const float*)d_in[0];
    const float* pair  = (const float*)d_in[1];
    const float* amask = (const float*)d_in[2];
    const float* dpos  = (const float*)d_in[3];
    const float* ln_g  = (const float*)d_in[4];
    const float* ln_b  = (const float*)d_in[5];
    const float* Wq    = (const float*)d_in[6];
    const float* Wk    = (const float*)d_in[7];
    const float* Wv    = (const float*)d_in[8];
    const float* pg    = (const float*)d_in[9];
    const float* pb    = (const float*)d_in[10];
    const float* Wb    = (const float*)d_in[11];
    const float* bbv   = (const float*)d_in[12];
    const float* Wf    = (const float*)d_in[13];
    float* out = (float*)d_out;

    char* ws = (char*)d_ws;
    float* xn = (float*)ws;                              // 4 MB
    float* Q  = (float*)(ws + (size_t)4 * 1048576);      // 4 MB
    float* K  = (float*)(ws + (size_t)8 * 1048576);      // 4 MB
    float* w  = (float*)(ws + (size_t)12 * 1048576);     // 256 KB
    unsigned short* Wbp = (unsigned short*)(ws + (size_t)12 * 1048576 + 262144); // 8 KB
    float* Sh  = (float*)(ws + (size_t)12 * 1048576 + 262144 + 8192);
    float* cbh = (float*)(ws + (size_t)12 * 1048576 + 262144 + 8192 + 128);

    ln_query_kernel<<<cB * cN, 256, 0, stream>>>(query, ln_g, ln_b, xn);
    setup_kernel<<<1, 256, 0, stream>>>(Wb, pg, pb, bbv, Wbp, Sh, cbh);
    hipMemsetAsync(w, 0, (size_t)cB * cN * cH * sizeof(float), stream);
    qkv_kernel<<<32 * 24, 256, 0, stream>>>(xn, Wq, Wk, Wv, Wf, Q, K, w);
    attn_kernel<<<cB * cN, 256, 0, stream>>>(pair, amask, dpos, Q, K, w, Wbp, Sh, cbh, out);
}